// Round 12
// baseline (160.999 us; speedup 1.0000x reference)
//
#include <hip/hip_runtime.h>
#include <math.h>

// SSIM loss, fused, single kernel. Round 12: r11 structure (OTW=116, OTH=32,
// SEGR=8, register-preload vertical burst, packed-f16 pipeline) +
//  - V stored as half4 per column (b64 LDS ops, half the DS instructions)
//  - final reduction fused via last-block pattern (atomic counter in d_ws,
//    fixed thread->index mapping => bit-deterministic scalar output)
// s=a+b, d=a-b reformulation; 21-op SSIM rational from raw window sums.
// Images: [16, 3, 512, 512] fp32. Output: scalar fp32.

typedef __fp16 half2_t __attribute__((ext_vector_type(2)));
typedef __fp16 half4_t __attribute__((ext_vector_type(4)));

constexpr int WIN  = 11;
constexpr int OTW  = 116;            // output tile width (5 tiles cover 512)
constexpr int OTH  = 32;             // output tile height
constexpr int VP   = 127;            // V cols (116+11); row = 1016 B
constexpr int SEGR = 8;              // output rows per wave segment
constexpr int SEGI = SEGR + WIN - 1; // 18 input rows per segment
constexpr int GPW  = 15;             // horizontal px per thread (8 x 15 >= 116)
constexpr int H = 512, W = 512;
constexpr int NPLANES = 16 * 3;
constexpr int GRIDX = (W + OTW - 1) / OTW;   // 5
constexpr int NB = GRIDX * (H / OTH) * NPLANES;  // 3840 blocks
constexpr long long NPIX = (long long)NPLANES * H * W;

// 21-op SSIM from raw window sums {ws, wd, wss, wdd}:
//   P=2ka*ws^2, Q=2ka*wd^2, U=2kc*wss, T=2kc*wdd  (ka=k1^2/4, kc=k1/4, k1=1/121)
//   num = (P-Q+C1)(U-T-(P-Q)+C2),  den = (P+Q+C1)(U+T-(P+Q)+C2)
__device__ __forceinline__ float ssim_px(float ws, float wd, float wss, float wdd) {
    const float C1 = 1e-4f;
    const float C2 = 9e-4f;
    const float k1 = 1.0f / 121.0f;
    const float c2a = 0.5f * k1 * k1;    // 2*ka
    const float c2c = 0.5f * k1;         // 2*kc
    const float P = (c2a * ws) * ws;
    const float Q = (c2a * wd) * wd;
    const float U = c2c * wss;
    const float T = c2c * wdd;
    const float r1 = P - Q;              // 2*mu1*mu2
    const float p1 = P + Q;              // mu1^2 + mu2^2
    const float t1 = U - T;              // 2*box(ab)
    const float u1 = U + T;              // box(a^2)+box(b^2)
    const float num = (r1 + C1) * (t1 - r1 + C2);
    const float den = (p1 + C1) * (u1 - p1 + C2);
    return num * __builtin_amdgcn_rcpf(den);
}

__device__ __forceinline__ float ssim4(half4_t a) {
    return ssim_px((float)a[0], (float)a[1], (float)a[2], (float)a[3]);
}

// Vertical box pass, one wave: 18 input rows -> 8 V rows, lane = 2 columns.
// Phase 1: burst-load all rows into registers (no inter-load dependencies).
// Phase 2: packed-f16 ring arithmetic entirely from registers.
template<bool XE, bool YE>
__device__ __forceinline__ void vpass(const float* __restrict__ ca,
                                      const float* __restrict__ cb,
                                      int gy0, bool xok0, bool xok1,
                                      int vrow0, int lane,
                                      half4_t (*V)[VP]) {
    float2 va[SEGI], vb[SEGI];
#pragma unroll
    for (int r = 0; r < SEGI; ++r) {
        if (YE) {
            const int gy = gy0 + r;
            if ((unsigned)gy < (unsigned)H) {     // wave-uniform
                va[r] = *(const float2*)(ca + (size_t)gy * W);
                vb[r] = *(const float2*)(cb + (size_t)gy * W);
            } else {
                va[r] = make_float2(0.f, 0.f);
                vb[r] = make_float2(0.f, 0.f);
            }
        } else {
            va[r] = *(const float2*)(ca + (size_t)(gy0 + r) * W);
            vb[r] = *(const float2*)(cb + (size_t)(gy0 + r) * W);
        }
    }

    half2_t r0[WIN], r1[WIN];
    half2_t asd0 = {(__fp16)0, (__fp16)0}, asq0 = asd0;
    half2_t asd1 = asd0, asq1 = asd0;
#pragma unroll
    for (int r = 0; r < SEGI; ++r) {
        float a0 = va[r].x, a1 = va[r].y, b0 = vb[r].x, b1 = vb[r].y;
        if (XE) {
            a0 = xok0 ? a0 : 0.f;  b0 = xok0 ? b0 : 0.f;
            a1 = xok1 ? a1 : 0.f;  b1 = xok1 ? b1 : 0.f;
        }
        const int i = r % WIN;                    // compile-time (unrolled)
        const half2_t p0 = __builtin_amdgcn_cvt_pkrtz(a0 + b0, a0 - b0);
        const half2_t p1 = __builtin_amdgcn_cvt_pkrtz(a1 + b1, a1 - b1);
        asd0 += p0;  asq0 += p0 * p0;
        asd1 += p1;  asq1 += p1 * p1;
        if (r >= WIN) {
            const half2_t o0 = r0[i], o1 = r1[i];
            asd0 -= o0;  asq0 -= o0 * o0;
            asd1 -= o1;  asq1 -= o1 * o1;
        }
        r0[i] = p0;  r1[i] = p1;
        if (r >= WIN - 1) {
            const int vr = vrow0 + r - (WIN - 1);
            const half4_t v0 = {asd0[0], asd0[1], asq0[0], asq0[1]};
            const half4_t v1 = {asd1[0], asd1[1], asq1[0], asq1[1]};
            V[vr][2 * lane]     = v0;
            V[vr][2 * lane + 1] = v1;
        }
    }
}

// Horizontal sliding pass over one 15-px run. CHK: right-image-edge masking.
template<bool CHK>
__device__ __forceinline__ float hpass(const half4_t (*V)[VP], int row,
                                       int x0, int gxb) {
    half4_t acc = {(__fp16)0, (__fp16)0, (__fp16)0, (__fp16)0};
#pragma unroll
    for (int r = 0; r < WIN; ++r)
        acc += V[row][x0 + 1 + r];
    float local = 0.0f;
    if (!CHK || gxb < W)
        local = ssim4(acc);
#pragma unroll
    for (int k = 1; k < GPW; ++k) {
        acc += V[row][x0 + k + WIN] - V[row][x0 + k];
        if ((x0 + k < OTW) && (!CHK || gxb + k < W))
            local += ssim4(acc);
    }
    return local;
}

__global__ __launch_bounds__(256, 4)
void ssim_tile_kernel(const float* __restrict__ img1,
                      const float* __restrict__ img2,
                      float* __restrict__ partials,
                      unsigned* __restrict__ counter,
                      float* __restrict__ out) {
    __shared__ half4_t V[OTH][VP];   // (ss,sd,sss,sdd) per col; 32,512 B
    __shared__ float wsum[4];
    __shared__ int lastblk;
    __shared__ double dsum[4];

    const int tid  = threadIdx.x;
    const int wave = tid >> 6;
    const int lane = tid & 63;
    const int tx0 = blockIdx.x * OTW;
    const int ty0 = blockIdx.y * OTH;
    const int plane = blockIdx.z;
    const float* __restrict__ pa = img1 + (size_t)plane * H * W;
    const float* __restrict__ pb = img2 + (size_t)plane * H * W;

    // ---- vertical pass: wave = 8-row segment, lane = 2 columns ----
    {
        // V col j <-> image col tx0 - 6 + j; lane l owns j = 2l, 2l+1.
        const int gxl = tx0 - 6 + 2 * lane;
        const bool xok0 = (unsigned)gxl < (unsigned)W;
        const bool xok1 = (unsigned)(gxl + 1) < (unsigned)W;
        const int gc = min(max(gxl, 0), W - 2);   // even -> 8B-aligned float2
        const int gy0 = ty0 + wave * SEGR - (WIN / 2);
        const int vrow0 = wave * SEGR;
        const bool xe = (blockIdx.x == 0) || (blockIdx.x == GRIDX - 1);
        const bool ye = (gy0 < 0) || (gy0 + SEGI > H);
        const float* __restrict__ ca = pa + gc;
        const float* __restrict__ cb = pb + gc;
        if (!xe) {
            if (!ye) vpass<false, false>(ca, cb, gy0, xok0, xok1, vrow0, lane, V);
            else     vpass<false, true >(ca, cb, gy0, xok0, xok1, vrow0, lane, V);
        } else {
            if (!ye) vpass<true, false>(ca, cb, gy0, xok0, xok1, vrow0, lane, V);
            else     vpass<true, true >(ca, cb, gy0, xok0, xok1, vrow0, lane, V);
        }
    }
    __syncthreads();

    // ---- horizontal sliding pass + SSIM: 32 rows x 8 groups of 15 px ----
    // Output px x (tile-rel) reads V cols x+1 .. x+11; max valid col = 126.
    // Group 7 (x0=105) over-runs past col 126 for k>=11; those outputs are
    // masked and the garbage never feeds a valid pixel.
    const int row = tid & 31;
    const int x0  = (tid >> 5) * GPW;
    const int gxb = tx0 + x0;
    float local;
    if (blockIdx.x != GRIDX - 1)
        local = hpass<false>(V, row, x0, gxb);
    else
        local = hpass<true >(V, row, x0, gxb);

    // ---- block reduction -> one partial per block ----
    for (int off = 32; off > 0; off >>= 1)
        local += __shfl_down(local, off);
    if (lane == 0) wsum[wave] = local;
    __syncthreads();

    const int bid = (blockIdx.z * gridDim.y + blockIdx.y) * gridDim.x + blockIdx.x;
    if (tid == 0) {
        partials[bid] = wsum[0] + wsum[1] + wsum[2] + wsum[3];
        __threadfence();                       // publish partial before count
        const unsigned c = atomicAdd(counter, 1u);
        lastblk = (c == (unsigned)(NB - 1));
    }
    __syncthreads();

    // ---- last arriving block: deterministic final reduction ----
    if (lastblk) {
        __threadfence();                       // acquire all partials
        double s = 0.0;
        for (int i = tid; i < NB; i += 256)
            s += (double)partials[i];
        for (int off = 32; off > 0; off >>= 1)
            s += __shfl_down(s, off);
        if (lane == 0) dsum[wave] = s;
        __syncthreads();
        if (tid == 0) {
            const double total = dsum[0] + dsum[1] + dsum[2] + dsum[3];
            out[0] = (float)(1.0 - total / (double)NPIX);
        }
    }
}

extern "C" void kernel_launch(void* const* d_in, const int* in_sizes, int n_in,
                              void* d_out, int out_size, void* d_ws, size_t ws_size,
                              hipStream_t stream) {
    const float* img1 = (const float*)d_in[0];
    const float* img2 = (const float*)d_in[1];
    float* out = (float*)d_out;
    unsigned* counter = (unsigned*)d_ws;                    // first 64 B
    float* partials = (float*)((char*)d_ws + 64);           // NB floats

    // zero the counter region each launch (graph-capturable, async)
    hipMemsetAsync(d_ws, 0, 64, stream);

    dim3 grid(GRIDX, H / OTH, NPLANES);  // 5 x 16 x 48 = 3840 blocks
    dim3 block(256);
    ssim_tile_kernel<<<grid, block, 0, stream>>>(img1, img2, partials,
                                                 counter, out);
}

// Round 13
// 34.140 us; speedup vs baseline: 4.7158x; 4.7158x over previous
//
#include <hip/hip_runtime.h>
#include <math.h>

// SSIM loss, fused. Round 13: r11 two-kernel structure (OTW=116, OTH=32,
// SEGR=8, register-preload vertical burst, packed-f16 pipeline) + half4 V
// (b64 LDS ops). NO device-scope fences in the hot path (r12 lesson: the
// last-block fence pattern serializes L2 maintenance on non-coherent XCDs).
// s=a+b, d=a-b reformulation; 21-op SSIM rational from raw window sums.
// Images: [16, 3, 512, 512] fp32. Output: scalar fp32.

typedef __fp16 half2_t __attribute__((ext_vector_type(2)));
typedef __fp16 half4_t __attribute__((ext_vector_type(4)));

constexpr int WIN  = 11;
constexpr int OTW  = 116;            // output tile width (5 tiles cover 512)
constexpr int OTH  = 32;             // output tile height
constexpr int VP   = 127;            // V cols (116+11); row = 1016 B
constexpr int SEGR = 8;              // output rows per wave segment
constexpr int SEGI = SEGR + WIN - 1; // 18 input rows per segment
constexpr int GPW  = 15;             // horizontal px per thread (8 x 15 >= 116)
constexpr int H = 512, W = 512;
constexpr int NPLANES = 16 * 3;
constexpr int GRIDX = (W + OTW - 1) / OTW;   // 5
constexpr long long NPIX = (long long)NPLANES * H * W;

// 21-op SSIM from raw window sums {ws, wd, wss, wdd}:
//   P=2ka*ws^2, Q=2ka*wd^2, U=2kc*wss, T=2kc*wdd  (ka=k1^2/4, kc=k1/4, k1=1/121)
//   num = (P-Q+C1)(U-T-(P-Q)+C2),  den = (P+Q+C1)(U+T-(P+Q)+C2)
__device__ __forceinline__ float ssim_px(float ws, float wd, float wss, float wdd) {
    const float C1 = 1e-4f;
    const float C2 = 9e-4f;
    const float k1 = 1.0f / 121.0f;
    const float c2a = 0.5f * k1 * k1;    // 2*ka
    const float c2c = 0.5f * k1;         // 2*kc
    const float P = (c2a * ws) * ws;
    const float Q = (c2a * wd) * wd;
    const float U = c2c * wss;
    const float T = c2c * wdd;
    const float r1 = P - Q;              // 2*mu1*mu2
    const float p1 = P + Q;              // mu1^2 + mu2^2
    const float t1 = U - T;              // 2*box(ab)
    const float u1 = U + T;              // box(a^2)+box(b^2)
    const float num = (r1 + C1) * (t1 - r1 + C2);
    const float den = (p1 + C1) * (u1 - p1 + C2);
    return num * __builtin_amdgcn_rcpf(den);
}

__device__ __forceinline__ float ssim4(half4_t a) {
    return ssim_px((float)a[0], (float)a[1], (float)a[2], (float)a[3]);
}

// Vertical box pass, one wave: 18 input rows -> 8 V rows, lane = 2 columns.
// Phase 1: burst-load all rows into registers (no inter-load dependencies).
// Phase 2: packed-f16 ring arithmetic entirely from registers.
template<bool XE, bool YE>
__device__ __forceinline__ void vpass(const float* __restrict__ ca,
                                      const float* __restrict__ cb,
                                      int gy0, bool xok0, bool xok1,
                                      int vrow0, int lane,
                                      half4_t (*V)[VP]) {
    float2 va[SEGI], vb[SEGI];
#pragma unroll
    for (int r = 0; r < SEGI; ++r) {
        if (YE) {
            const int gy = gy0 + r;
            if ((unsigned)gy < (unsigned)H) {     // wave-uniform
                va[r] = *(const float2*)(ca + (size_t)gy * W);
                vb[r] = *(const float2*)(cb + (size_t)gy * W);
            } else {
                va[r] = make_float2(0.f, 0.f);
                vb[r] = make_float2(0.f, 0.f);
            }
        } else {
            va[r] = *(const float2*)(ca + (size_t)(gy0 + r) * W);
            vb[r] = *(const float2*)(cb + (size_t)(gy0 + r) * W);
        }
    }

    half2_t r0[WIN], r1[WIN];
    half2_t asd0 = {(__fp16)0, (__fp16)0}, asq0 = asd0;
    half2_t asd1 = asd0, asq1 = asd0;
#pragma unroll
    for (int r = 0; r < SEGI; ++r) {
        float a0 = va[r].x, a1 = va[r].y, b0 = vb[r].x, b1 = vb[r].y;
        if (XE) {
            a0 = xok0 ? a0 : 0.f;  b0 = xok0 ? b0 : 0.f;
            a1 = xok1 ? a1 : 0.f;  b1 = xok1 ? b1 : 0.f;
        }
        const int i = r % WIN;                    // compile-time (unrolled)
        const half2_t p0 = __builtin_amdgcn_cvt_pkrtz(a0 + b0, a0 - b0);
        const half2_t p1 = __builtin_amdgcn_cvt_pkrtz(a1 + b1, a1 - b1);
        asd0 += p0;  asq0 += p0 * p0;
        asd1 += p1;  asq1 += p1 * p1;
        if (r >= WIN) {
            const half2_t o0 = r0[i], o1 = r1[i];
            asd0 -= o0;  asq0 -= o0 * o0;
            asd1 -= o1;  asq1 -= o1 * o1;
        }
        r0[i] = p0;  r1[i] = p1;
        if (r >= WIN - 1) {
            const int vr = vrow0 + r - (WIN - 1);
            const half4_t v0 = {asd0[0], asd0[1], asq0[0], asq0[1]};
            const half4_t v1 = {asd1[0], asd1[1], asq1[0], asq1[1]};
            V[vr][2 * lane]     = v0;
            V[vr][2 * lane + 1] = v1;
        }
    }
}

// Horizontal sliding pass over one 15-px run. CHK: right-image-edge masking.
template<bool CHK>
__device__ __forceinline__ float hpass(const half4_t (*V)[VP], int row,
                                       int x0, int gxb) {
    half4_t acc = {(__fp16)0, (__fp16)0, (__fp16)0, (__fp16)0};
#pragma unroll
    for (int r = 0; r < WIN; ++r)
        acc += V[row][x0 + 1 + r];
    float local = 0.0f;
    if (!CHK || gxb < W)
        local = ssim4(acc);
#pragma unroll
    for (int k = 1; k < GPW; ++k) {
        acc += V[row][x0 + k + WIN] - V[row][x0 + k];
        if ((x0 + k < OTW) && (!CHK || gxb + k < W))
            local += ssim4(acc);
    }
    return local;
}

__global__ __launch_bounds__(256, 4)
void ssim_tile_kernel(const float* __restrict__ img1,
                      const float* __restrict__ img2,
                      float* __restrict__ partials) {
    __shared__ half4_t V[OTH][VP];   // (ss,sd,sss,sdd) per col; 32,512 B
    __shared__ float wsum[4];

    const int tid  = threadIdx.x;
    const int wave = tid >> 6;
    const int lane = tid & 63;
    const int tx0 = blockIdx.x * OTW;
    const int ty0 = blockIdx.y * OTH;
    const int plane = blockIdx.z;
    const float* __restrict__ pa = img1 + (size_t)plane * H * W;
    const float* __restrict__ pb = img2 + (size_t)plane * H * W;

    // ---- vertical pass: wave = 8-row segment, lane = 2 columns ----
    {
        // V col j <-> image col tx0 - 6 + j; lane l owns j = 2l, 2l+1.
        const int gxl = tx0 - 6 + 2 * lane;
        const bool xok0 = (unsigned)gxl < (unsigned)W;
        const bool xok1 = (unsigned)(gxl + 1) < (unsigned)W;
        const int gc = min(max(gxl, 0), W - 2);   // even -> 8B-aligned float2
        const int gy0 = ty0 + wave * SEGR - (WIN / 2);
        const int vrow0 = wave * SEGR;
        const bool xe = (blockIdx.x == 0) || (blockIdx.x == GRIDX - 1);
        const bool ye = (gy0 < 0) || (gy0 + SEGI > H);
        const float* __restrict__ ca = pa + gc;
        const float* __restrict__ cb = pb + gc;
        if (!xe) {
            if (!ye) vpass<false, false>(ca, cb, gy0, xok0, xok1, vrow0, lane, V);
            else     vpass<false, true >(ca, cb, gy0, xok0, xok1, vrow0, lane, V);
        } else {
            if (!ye) vpass<true, false>(ca, cb, gy0, xok0, xok1, vrow0, lane, V);
            else     vpass<true, true >(ca, cb, gy0, xok0, xok1, vrow0, lane, V);
        }
    }
    __syncthreads();

    // ---- horizontal sliding pass + SSIM: 32 rows x 8 groups of 15 px ----
    // Output px x (tile-rel) reads V cols x+1 .. x+11; max valid col = 126.
    // Group 7 (x0=105) over-runs past col 126 for k>=11; those outputs are
    // masked and the garbage never feeds a valid pixel.
    const int row = tid & 31;
    const int x0  = (tid >> 5) * GPW;
    const int gxb = tx0 + x0;
    float local;
    if (blockIdx.x != GRIDX - 1)
        local = hpass<false>(V, row, x0, gxb);
    else
        local = hpass<true >(V, row, x0, gxb);

    // ---- block reduction, one partial per block ----
    for (int off = 32; off > 0; off >>= 1)
        local += __shfl_down(local, off);
    if (lane == 0) wsum[wave] = local;
    __syncthreads();
    if (tid == 0) {
        const int bid = (blockIdx.z * gridDim.y + blockIdx.y) * gridDim.x + blockIdx.x;
        partials[bid] = wsum[0] + wsum[1] + wsum[2] + wsum[3];
    }
}

__global__ __launch_bounds__(1024)
void ssim_reduce_kernel(const float4* __restrict__ partials4, int n4,
                        float* __restrict__ out) {
    double s = 0.0;
    for (int i = threadIdx.x; i < n4; i += 1024) {
        const float4 p = partials4[i];
        s += (double)p.x + (double)p.y + (double)p.z + (double)p.w;
    }
    for (int off = 32; off > 0; off >>= 1)
        s += __shfl_down(s, off);
    __shared__ double wsum[16];
    if ((threadIdx.x & 63) == 0) wsum[threadIdx.x >> 6] = s;
    __syncthreads();
    if (threadIdx.x == 0) {
        double total = 0.0;
        for (int w = 0; w < 16; ++w) total += wsum[w];
        out[0] = (float)(1.0 - total / (double)NPIX);
    }
}

extern "C" void kernel_launch(void* const* d_in, const int* in_sizes, int n_in,
                              void* d_out, int out_size, void* d_ws, size_t ws_size,
                              hipStream_t stream) {
    const float* img1 = (const float*)d_in[0];
    const float* img2 = (const float*)d_in[1];
    float* out = (float*)d_out;
    float* partials = (float*)d_ws;

    dim3 grid(GRIDX, H / OTH, NPLANES);  // 5 x 16 x 48 = 3840 blocks
    dim3 block(256);
    ssim_tile_kernel<<<grid, block, 0, stream>>>(img1, img2, partials);

    const int nblocks = GRIDX * (H / OTH) * NPLANES;   // 3840, divisible by 4
    ssim_reduce_kernel<<<1, 1024, 0, stream>>>((const float4*)partials,
                                               nblocks / 4, out);
}